// Round 1
// baseline (91.122 us; speedup 1.0000x reference)
//
#include <hip/hip_runtime.h>

// QuantumAttention: B=8, S=2048, E=8, H=2, D=4, NQ=8
// Quantum circuit reduced to closed form:
//   c_w = cos(tok[w] + tok[w%4]);  z[0] = c1..c7,  z[q>=1] = c0..cq
// Attention: full softmax over S=2048, one-pass (no max subtraction needed:
// |score| <= ~15, exp fits fp32 comfortably).

#define SS 2048
#define EE 8

// One block per (b, h, row-block of 64). 512 threads = 64 rows x 8 j-slices.
// LDS: K,V for this (b,h): 2048 x {k0..3, v0..3} fp32 = 64 KB (2 blocks/CU).
extern "C" __global__ __launch_bounds__(512)
void qa_attn(const float* __restrict__ x, const float* __restrict__ Wq,
             const float* __restrict__ Wk, const float* __restrict__ Wv,
             float* __restrict__ AO) {
    __shared__ __align__(16) char smem[65536];
    float4* kv4  = (float4*)smem;                 // [2048][2] float4
    float*  pden = (float*)smem;                  // overlay after j-loop: [8][64]
    float4* pacc = (float4*)(smem + 2048 * 4);    // overlay: [8][64] float4

    const int bid = blockIdx.x;
    const int rb  = bid & 31;         // row-block 0..31
    const int h   = (bid >> 5) & 1;   // head
    const int b   = bid >> 6;         // batch
    const int tid = threadIdx.x;
    const int hoff = h * 4;           // row offset into Wk/Wv/Wq (f = h*D + d)

    // ---- stage K,V for (b,h) into LDS (fused QKV projection) ----
    #pragma unroll
    for (int u = 0; u < 4; ++u) {
        const int j = tid + u * 512;
        const float* xp = x + ((size_t)(b * SS + j)) * EE;
        float4 x0 = *(const float4*)xp;
        float4 x1 = *(const float4*)(xp + 4);
        float xv[8] = {x0.x, x0.y, x0.z, x0.w, x1.x, x1.y, x1.z, x1.w};
        float kk[4], vv[4];
        #pragma unroll
        for (int d = 0; d < 4; ++d) {
            const float* wkr = Wk + (hoff + d) * EE;
            const float* wvr = Wv + (hoff + d) * EE;
            float sk = 0.f, sv = 0.f;
            #pragma unroll
            for (int e = 0; e < 8; ++e) { sk += xv[e] * wkr[e]; sv += xv[e] * wvr[e]; }
            kk[d] = sk; vv[d] = sv;
        }
        kv4[j * 2]     = make_float4(kk[0], kk[1], kk[2], kk[3]);
        kv4[j * 2 + 1] = make_float4(vv[0], vv[1], vv[2], vv[3]);
    }

    // ---- own q (each of the 8 slice-threads for a row computes it redundantly) ----
    const int r  = tid & 63;    // row within tile (= lane)
    const int sl = tid >> 6;    // j-slice (= wave id)
    const int i  = rb * 64 + r; // query row
    float q[4];
    {
        const float* xp = x + ((size_t)(b * SS + i)) * EE;
        float4 x0 = *(const float4*)xp;
        float4 x1 = *(const float4*)(xp + 4);
        float xv[8] = {x0.x, x0.y, x0.z, x0.w, x1.x, x1.y, x1.z, x1.w};
        #pragma unroll
        for (int d = 0; d < 4; ++d) {
            const float* wqr = Wq + (hoff + d) * EE;
            float s = 0.f;
            #pragma unroll
            for (int e = 0; e < 8; ++e) s += xv[e] * wqr[e];
            q[d] = s;
        }
    }
    __syncthreads();

    // ---- one-pass softmax + PV over this thread's j-slice ----
    float den = 0.f, a0 = 0.f, a1 = 0.f, a2 = 0.f, a3 = 0.f;
    const int j0 = sl * 256;
    #pragma unroll 4
    for (int j = j0; j < j0 + 256; ++j) {
        float4 kk = kv4[j * 2];      // broadcast read (all lanes same addr)
        float4 vv = kv4[j * 2 + 1];
        float s = 0.5f * (q[0] * kk.x + q[1] * kk.y + q[2] * kk.z + q[3] * kk.w);
        float e = __expf(s);
        den += e;
        a0 += e * vv.x; a1 += e * vv.y; a2 += e * vv.z; a3 += e * vv.w;
    }

    // ---- combine the 8 slice-partials per row (plain sums; no max used) ----
    __syncthreads();   // everyone done reading kv4 before overlay writes
    pden[sl * 64 + r] = den;
    pacc[sl * 64 + r] = make_float4(a0, a1, a2, a3);
    __syncthreads();
    if (sl == 0) {
        #pragma unroll
        for (int u = 1; u < 8; ++u) {
            den += pden[u * 64 + r];
            float4 p = pacc[u * 64 + r];
            a0 += p.x; a1 += p.y; a2 += p.z; a3 += p.w;
        }
        const float inv = 1.f / den;
        *(float4*)(AO + (((size_t)(b * SS + i)) * 2 + h) * 4) =
            make_float4(a0 * inv, a1 * inv, a2 * inv, a3 * inv);
    }
}

// Per-token closed-form quantum measurement + Wo projection.
extern "C" __global__ __launch_bounds__(256)
void qa_quantum(const float* __restrict__ AO, const float* __restrict__ Wo,
                float* __restrict__ out) {
    __shared__ float wo[64];
    const int tid = threadIdx.x;
    if (tid < 64) wo[tid] = Wo[tid];
    __syncthreads();

    const int g = blockIdx.x * 256 + tid;   // token 0..16383
    const float* tp = AO + (size_t)g * 8;
    float4 t0 = *(const float4*)tp;
    float4 t1 = *(const float4*)(tp + 4);
    float tok[8] = {t0.x, t0.y, t0.z, t0.w, t1.x, t1.y, t1.z, t1.w};

    float c[8];
    #pragma unroll
    for (int w = 0; w < 8; ++w) c[w] = __cosf(tok[w] + tok[w & 3]);

    float z[8];
    float p = 1.f;
    #pragma unroll
    for (int qq = 1; qq < 8; ++qq) { p *= c[qq]; z[qq] = p; }
    z[0] = p;                       // c1..c7
    #pragma unroll
    for (int qq = 1; qq < 8; ++qq) z[qq] *= c[0];   // c0..cq

    float y[8];
    #pragma unroll
    for (int f = 0; f < 8; ++f) {
        float s = 0.f;
        #pragma unroll
        for (int qq = 0; qq < 8; ++qq) s += z[qq] * wo[f * 8 + qq];
        y[f] = s;
    }
    float* op = out + (size_t)g * 8;
    *(float4*)op       = make_float4(y[0], y[1], y[2], y[3]);
    *(float4*)(op + 4) = make_float4(y[4], y[5], y[6], y[7]);
}

extern "C" void kernel_launch(void* const* d_in, const int* in_sizes, int n_in,
                              void* d_out, int out_size, void* d_ws, size_t ws_size,
                              hipStream_t stream) {
    const float* x  = (const float*)d_in[0];
    const float* Wq = (const float*)d_in[1];
    const float* Wk = (const float*)d_in[2];
    const float* Wv = (const float*)d_in[3];
    const float* Wo = (const float*)d_in[4];
    float* out = (float*)d_out;
    float* AO  = (float*)d_ws;   // 16384 tokens x 8 floats = 512 KB

    qa_attn<<<dim3(512), dim3(512), 0, stream>>>(x, Wq, Wk, Wv, AO);
    qa_quantum<<<dim3(64), dim3(256), 0, stream>>>(AO, Wo, out);
}